// Round 2
// baseline (512.276 us; speedup 1.0000x reference)
//
#include <hip/hip_runtime.h>
#include <hip/hip_bf16.h>

typedef __attribute__((ext_vector_type(4))) float  f32x4;
typedef __attribute__((ext_vector_type(8))) short  bf16x8;
typedef unsigned short u16;

#define ALPHA 0.2f
#define NN 8192
#define FF 128
#define LOG2E 1.4426950408889634f

#if __has_builtin(__builtin_amdgcn_exp2f)
#define EXP2F(x) __builtin_amdgcn_exp2f(x)
#else
#define EXP2F(x) __expf((x) * 0.6931471805599453f)
#endif

// ---------------- K1: h = x@W (fp32), write hT (bf16, transposed), s1l, s2l --
// s1l/s2l are pre-scaled by log2(e): leakyrelu(t)*c == leakyrelu(t*c) for c>0,
// so exp(lrelu(s1+s2)) == exp2(lrelu(s1l+s2l)).
extern "C" __global__ void __launch_bounds__(256)
gat_pre(const float* __restrict__ x, const float* __restrict__ Wm,
        const float* __restrict__ av, u16* __restrict__ hT,
        float* __restrict__ s1v, float* __restrict__ s2v) {
  __shared__ float xs[16][256];   // 16 KB
  __shared__ float hs[16][128];   // 8 KB
  const int t  = threadIdx.x;
  const int i0 = blockIdx.x * 16;

  { // stage x tile, coalesced
    const int r = t >> 4, c0 = (t & 15) * 16;
    const f32x4* src = (const f32x4*)(x + (size_t)(i0 + r) * 256 + c0);
    f32x4* dst = (f32x4*)&xs[r][c0];
#pragma unroll
    for (int m = 0; m < 4; ++m) dst[m] = src[m];
  }
  __syncthreads();

  { // h: thread = col c (0..127) x row-half rh; 8 rows each
    const int c = t & 127, rh = t >> 7;
    float acc[8] = {0.f,0.f,0.f,0.f,0.f,0.f,0.f,0.f};
    for (int k = 0; k < 256; ++k) {
      const float wk = Wm[k * 128 + c];   // coalesced, L2-hot
#pragma unroll
      for (int r = 0; r < 8; ++r) acc[r] = fmaf(xs[rh * 8 + r][k], wk, acc[r]);
    }
#pragma unroll
    for (int r = 0; r < 8; ++r) hs[rh * 8 + r][c] = acc[r];
  }
  __syncthreads();

  { // write transposed bf16 copy: hT[c][i]
    const int c = t >> 1, rr = (t & 1) * 8;
    u16 u[8];
#pragma unroll
    for (int k = 0; k < 8; ++k) {
      __hip_bfloat16 b = __float2bfloat16(hs[rr + k][c]);
      u[k] = *reinterpret_cast<u16*>(&b);
    }
    *(uint4*)(hT + (size_t)c * NN + i0 + rr) = *(const uint4*)u;
  }

  { // s1/s2 per row: 16 threads per row, shfl reduce; scale by log2e
    const int r = t >> 4, q = t & 15;
    float p1 = 0.f, p2 = 0.f;
#pragma unroll
    for (int m = 0; m < 8; ++m) {
      const int c = q * 8 + m;
      const float hv = hs[r][c];
      p1 = fmaf(hv, av[c], p1);
      p2 = fmaf(hv, av[128 + c], p2);
    }
    p1 += __shfl_xor(p1, 1); p1 += __shfl_xor(p1, 2);
    p1 += __shfl_xor(p1, 4); p1 += __shfl_xor(p1, 8);
    p2 += __shfl_xor(p2, 1); p2 += __shfl_xor(p2, 2);
    p2 += __shfl_xor(p2, 4); p2 += __shfl_xor(p2, 8);
    if (q == 0) { s1v[i0 + r] = p1 * LOG2E; s2v[i0 + r] = p2 * LOG2E; }
  }
}

// ---------------- K2: barrier-free fused masked-softmax + PV via MFMA --------
// 512 blocks x 512 thr (8 waves, 2 blocks/CU, 4 waves/SIMD). Block owns a
// 16-row strip; wave wv owns j in [wv*1024, wv*1024+1024). A-fragment (exp
// weights) generated per-lane in registers (A layout: row=lane&15,
// k=(lane>>4)*8+e). B read directly from L2-resident hT. No LDS / barriers
// in the main loop; single 8-way partial reduction at the end.
extern "C" __global__ void __launch_bounds__(512, 4)
gat_main(const float* __restrict__ adj, const u16* __restrict__ hT,
         const float* __restrict__ s1l, const float* __restrict__ s2l,
         float* __restrict__ out) {
  __shared__ float accp[8][16][132];   // 67.6 KB (132: 16B-aligned rows)
  __shared__ float denp[8][16];

  const int t    = threadIdx.x;
  const int lane = t & 63;
  const int wv   = t >> 6;
  const int cA   = lane & 15;          // A-row / B-col within fragment
  const int kg   = lane >> 4;          // k-group 0..3
  const int i0   = blockIdx.x * 16;
  const int jq0  = wv * (NN / 8);

  const float s1i = s1l[i0 + cA];
  const float* adjp = adj + (size_t)(i0 + cA) * NN + jq0 + kg * 8;
  const float* s2p  = s2l + jq0 + kg * 8;
  const u16*   hTb  = hT + (size_t)cA * NN + jq0 + kg * 8;

  f32x4 acc[8];
#pragma unroll
  for (int f = 0; f < 8; ++f) acc[f] = (f32x4){0.f, 0.f, 0.f, 0.f};
  float den = 0.f;

  // prefetch A inputs for step 0
  f32x4 a0 = *(const f32x4*)(adjp);
  f32x4 a1 = *(const f32x4*)(adjp + 4);
  f32x4 z0 = *(const f32x4*)(s2p);
  f32x4 z1 = *(const f32x4*)(s2p + 4);

  for (int st = 0; st < 32; ++st) {
    // B fragments for this step (L2-hot); consumed after the exp block
    bf16x8 bf[8];
#pragma unroll
    for (int f = 0; f < 8; ++f)
      bf[f] = *(const bf16x8*)(hTb + (size_t)f * 16 * NN + st * 32);

    // A fragment: w = adj * exp2(lrelu(s1l+s2l))   (adj is exactly 0/1)
    bf16x8 af;
    float dstep = 0.f;
#pragma unroll
    for (int e = 0; e < 8; ++e) {
      const float adv = (e < 4) ? a0[e] : a1[e - 4];
      const float tz  = s1i + ((e < 4) ? z0[e] : z1[e - 4]);
      const float fz  = fmaxf(tz, ALPHA * tz);
      const float w8  = adv * EXP2F(fz);
      dstep += w8;
      __hip_bfloat16 hb = __float2bfloat16(w8);
      af[e] = *reinterpret_cast<short*>(&hb);
    }
    den += dstep;

    // prefetch next step's A inputs (one full step of cover ≈ exp+MFMA phase)
    if (st < 31) {
      const float* ap = adjp + (st + 1) * 32;
      a0 = *(const f32x4*)(ap);
      a1 = *(const f32x4*)(ap + 4);
      const float* zp = s2p + (st + 1) * 32;
      z0 = *(const f32x4*)(zp);
      z1 = *(const f32x4*)(zp + 4);
    }

#pragma unroll
    for (int f = 0; f < 8; ++f)
      acc[f] = __builtin_amdgcn_mfma_f32_16x16x32_bf16(af, bf[f], acc[f], 0, 0, 0);
  }

  // den: lanes sharing cA (kg groups) hold disjoint j-chunks of row cA
  den += __shfl_xor(den, 16);
  den += __shfl_xor(den, 32);
  if (kg == 0) denp[wv][cA] = den;

  // C/D layout: row=(lane>>4)*4+r, col=f*16+(lane&15)
#pragma unroll
  for (int f = 0; f < 8; ++f)
#pragma unroll
    for (int r = 0; r < 4; ++r)
      accp[wv][kg * 4 + r][f * 16 + cA] = acc[f][r];

  __syncthreads();

  { // 8-way reduce + softmax divide + coalesced f32x4 store
    const int row = t >> 5;
    const int c0  = (t & 31) * 4;
    float dv = 0.f;
#pragma unroll
    for (int w = 0; w < 8; ++w) dv += denp[w][row];
    f32x4 s = {0.f, 0.f, 0.f, 0.f};
#pragma unroll
    for (int w = 0; w < 8; ++w) s += *(const f32x4*)&accp[w][row][c0];
    s.x /= dv; s.y /= dv; s.z /= dv; s.w /= dv;
    *(f32x4*)(out + (size_t)(i0 + row) * FF + c0) = s;
  }
}

extern "C" void kernel_launch(void* const* d_in, const int* in_sizes, int n_in,
                              void* d_out, int out_size, void* d_ws, size_t ws_size,
                              hipStream_t stream) {
  const float* x   = (const float*)d_in[0];
  const float* adj = (const float*)d_in[1];
  const float* Wm  = (const float*)d_in[2];
  const float* av  = (const float*)d_in[3];
  float* out = (float*)d_out;

  u16*   hT  = (u16*)d_ws;                              // 128*8192*2 = 2 MB
  float* s1v = (float*)((char*)d_ws + (size_t)FF * NN * 2);
  float* s2v = s1v + NN;

  gat_pre <<<NN / 16, 256, 0, stream>>>(x, Wm, av, hT, s1v, s2v);
  gat_main<<<NN / 16, 512, 0, stream>>>(adj, hT, s1v, s2v, out);
}

// Round 3
// 395.103 us; speedup vs baseline: 1.2966x; 1.2966x over previous
//
#include <hip/hip_runtime.h>
#include <hip/hip_bf16.h>

typedef __attribute__((ext_vector_type(4))) float  f32x4;
typedef __attribute__((ext_vector_type(8))) short  bf16x8;
typedef unsigned short u16;

#define ALPHA 0.2f
#define NN 8192
#define FF 128
#define LOG2E 1.4426950408889634f
#define AS1 __attribute__((address_space(1)))
#define AS3 __attribute__((address_space(3)))

__device__ __forceinline__ u16 f2b(float f) {
  __hip_bfloat16 hb = __float2bfloat16(f);
  return *reinterpret_cast<u16*>(&hb);
}

// ---------- K0: convert x -> bf16 (xb), W -> bf16 transposed (WTb) ----------
extern "C" __global__ void __launch_bounds__(256)
wt_cvt(const float* __restrict__ x, const float* __restrict__ Wm,
       u16* __restrict__ xb, u16* __restrict__ WTb) {
  const int id = blockIdx.x * 256 + threadIdx.x;
  if (blockIdx.x < 2048) {                 // x: 2M elems, 4 per thread
    const f32x4 v = *(const f32x4*)(x + (size_t)id * 4);
    uint2 p;
    p.x = f2b(v.x) | ((unsigned)f2b(v.y) << 16);
    p.y = f2b(v.z) | ((unsigned)f2b(v.w) << 16);
    *(uint2*)(xb + (size_t)id * 4) = p;
  } else {                                  // WT: 32768 elems, 1 per thread
    const int o = id - 2048 * 256;          // o = c*256 + k
    const int c = o >> 8, k = o & 255;
    WTb[o] = f2b(Wm[k * 128 + c]);
  }
}

// ---------- K1: h = x@W via MFMA (fp32 acc); write hT bf16, s1l, s2l --------
extern "C" __global__ void __launch_bounds__(256)
gat_h(const u16* __restrict__ xb, const u16* __restrict__ WTb,
      const float* __restrict__ av, u16* __restrict__ hT,
      float* __restrict__ s1v, float* __restrict__ s2v) {
  __shared__ float hs[16][128];
  const int t = threadIdx.x, lane = t & 63, wv = t >> 6;
  const int i0 = blockIdx.x * 16;
  const int fr = lane & 15, kg = lane >> 4;

  f32x4 acc0 = {0.f,0.f,0.f,0.f}, acc1 = {0.f,0.f,0.f,0.f};
  const u16* xp  = xb  + (size_t)(i0 + fr) * 256 + kg * 8;
  const u16* b0p = WTb + (size_t)(wv * 32 + fr) * 256 + kg * 8;
  const u16* b1p = b0p + 16 * 256;
#pragma unroll
  for (int ks = 0; ks < 8; ++ks) {
    const bf16x8 A  = *(const bf16x8*)(xp  + ks * 32);
    const bf16x8 B0 = *(const bf16x8*)(b0p + ks * 32);
    const bf16x8 B1 = *(const bf16x8*)(b1p + ks * 32);
    acc0 = __builtin_amdgcn_mfma_f32_16x16x32_bf16(A, B0, acc0, 0, 0, 0);
    acc1 = __builtin_amdgcn_mfma_f32_16x16x32_bf16(A, B1, acc1, 0, 0, 0);
  }
#pragma unroll
  for (int r = 0; r < 4; ++r) {            // C/D: row=(lane>>4)*4+r, col=lane&15
    hs[kg * 4 + r][wv * 32 + fr]      = acc0[r];
    hs[kg * 4 + r][wv * 32 + 16 + fr] = acc1[r];
  }
  __syncthreads();

  { // hT[c][i] bf16, 16B stores
    const int c = t >> 1, rr = (t & 1) * 8;
    u16 u[8];
#pragma unroll
    for (int m = 0; m < 8; ++m) u[m] = f2b(hs[rr + m][c]);
    *(uint4*)(hT + (size_t)c * NN + i0 + rr) = *(const uint4*)u;
  }
  { // s1/s2 (pre-scaled by log2e)
    const int r = t >> 4, q = t & 15;
    float p1 = 0.f, p2 = 0.f;
#pragma unroll
    for (int m = 0; m < 8; ++m) {
      const int c = q * 8 + m;
      const float hv = hs[r][c];
      p1 = fmaf(hv, av[c], p1);
      p2 = fmaf(hv, av[128 + c], p2);
    }
    p1 += __shfl_xor(p1, 1); p1 += __shfl_xor(p1, 2);
    p1 += __shfl_xor(p1, 4); p1 += __shfl_xor(p1, 8);
    p2 += __shfl_xor(p2, 1); p2 += __shfl_xor(p2, 2);
    p2 += __shfl_xor(p2, 4); p2 += __shfl_xor(p2, 8);
    if (q == 0) { s1v[i0 + r] = p1 * LOG2E; s2v[i0 + r] = p2 * LOG2E; }
  }
}

// ---------- K2: fused masked-softmax + PV; LDS double-buffer, counted vmcnt --
// 512 blocks x 512 thr (8 waves). Block: 16 rows x full j, JB=128 (64 chunks).
// Wave wv owns output cols wv*16..+16 (one 16x16 MFMA tile, acc = 1 f32x4).
// h tile: global_load_lds with pre-swizzled source; w tile: in-reg exp -> LDS.
extern "C" __global__ void __launch_bounds__(512, 4)
gat_main(const float* __restrict__ adj, const u16* __restrict__ hT,
         const float* __restrict__ s1l, const float* __restrict__ s2l,
         float* __restrict__ out) {
  __shared__ u16 hl[2][128 * 128];   // 2 x 32 KB, [f][j] bf16, swizzled
  __shared__ u16 wl[2][16 * 128];    // 2 x 4 KB,  [i][j] bf16, swizzled

  const int t = threadIdx.x, lane = t & 63, wv = t >> 6;
  const int i0 = blockIdx.x * 16;
  const int gr = t >> 5;             // w-gen row 0..15
  const int gj = (t & 31) * 4;       // w-gen j-offset
  const int c16 = (t & 31) >> 1, half = t & 1;
  const int r0 = wv * 16;            // h-stage row base
  const int srow = lane >> 4, scol = lane & 15;
  const int fr = lane & 15, kg = lane >> 4;
  const int bcol = wv * 16 + fr;     // this wave's B-row / out col

  const float s1i = s1l[i0 + gr];
  const float* adjp = adj + (size_t)(i0 + gr) * NN + gj;

  f32x4 acc = {0.f, 0.f, 0.f, 0.f};
  float den = 0.f;
  f32x4 a4, z4;

  // ---- helpers ----
  auto stage_h = [&](int b, int jn) {
#pragma unroll
    for (int q = 0; q < 4; ++q) {
      const int r = r0 + q * 4 + srow;
      const u16* g = hT + (size_t)r * NN + jn + ((scol ^ (r & 7)) << 3);
      __builtin_amdgcn_global_load_lds((const AS1 void*)g,
          (AS3 void*)&hl[b][(r0 + q * 4) * 128], 16, 0, 0);
    }
    __builtin_amdgcn_sched_barrier(0);   // pin: later vmem stays after DMA
  };
  auto wgen = [&](int b) {
    float w0, w1, w2, w3;
    { float tz = s1i + z4.x; float fz = fmaxf(tz, ALPHA * tz); w0 = a4.x * exp2f(fz); }
    { float tz = s1i + z4.y; float fz = fmaxf(tz, ALPHA * tz); w1 = a4.y * exp2f(fz); }
    { float tz = s1i + z4.z; float fz = fmaxf(tz, ALPHA * tz); w2 = a4.z * exp2f(fz); }
    { float tz = s1i + z4.w; float fz = fmaxf(tz, ALPHA * tz); w3 = a4.w * exp2f(fz); }
    den += (w0 + w1) + (w2 + w3);
    uint2 p;
    p.x = f2b(w0) | ((unsigned)f2b(w1) << 16);
    p.y = f2b(w2) | ((unsigned)f2b(w3) << 16);
    char* base = (char*)&wl[b][0];
    *(uint2*)(base + gr * 256 + ((c16 ^ (gr & 7)) << 4) + half * 8) = p;
  };
  auto mmstep = [&](int b) {
    const char* wb = (const char*)&wl[b][0];
    const char* hb = (const char*)&hl[b][0];
#pragma unroll
    for (int ks = 0; ks < 4; ++ks) {
      const int cg = ks * 4 + kg;
      const bf16x8 A = *(const bf16x8*)(wb + fr * 256 + ((cg ^ (fr & 7)) << 4));
      const bf16x8 B = *(const bf16x8*)(hb + bcol * 256 + ((cg ^ (bcol & 7)) << 4));
      acc = __builtin_amdgcn_mfma_f32_16x16x32_bf16(A, B, acc, 0, 0, 0);
    }
  };

  // ---- prologue: chunk 0 staged+generated, chunk1 adj/s2 in flight ----
  stage_h(0, 0);
  a4 = *(const f32x4*)(adjp);
  z4 = *(const f32x4*)(s2l + gj);
  wgen(0);                                  // auto-wait drains everything
  a4 = *(const f32x4*)(adjp + 128);
  z4 = *(const f32x4*)(s2l + 128 + gj);
  asm volatile("s_waitcnt lgkmcnt(0)" ::: "memory");
  __builtin_amdgcn_s_barrier();

  // ---- main loop: it = 0..61 full pipeline ----
  for (int it = 0; it < 62; ++it) {
    const int cb = it & 1, nb = cb ^ 1;
    stage_h(nb, (it + 1) * 128);
    wgen(nb);                               // consumes chunk it+1 regs
    a4 = *(const f32x4*)(adjp + (it + 2) * 128);
    z4 = *(const f32x4*)(s2l + (it + 2) * 128 + gj);
    mmstep(cb);
    // drain the 4 h-stage DMAs; keep adj/s2 (2) in flight across barrier
    asm volatile("s_waitcnt vmcnt(2) lgkmcnt(0)" ::: "memory");
    __builtin_amdgcn_s_barrier();
  }
  // ---- it = 62: stage+gen chunk 63, no more prefetch ----
  stage_h(1, 63 * 128);
  wgen(1);
  mmstep(0);
  asm volatile("s_waitcnt vmcnt(0) lgkmcnt(0)" ::: "memory");
  __builtin_amdgcn_s_barrier();
  // ---- it = 63: compute only ----
  mmstep(1);
  asm volatile("s_waitcnt lgkmcnt(0)" ::: "memory");
  __builtin_amdgcn_s_barrier();

  // ---- epilogue: den reduce (32 lanes per row), divide, store ----
  den += __shfl_xor(den, 1);  den += __shfl_xor(den, 2);
  den += __shfl_xor(den, 4);  den += __shfl_xor(den, 8);
  den += __shfl_xor(den, 16);
  float* denl = (float*)&wl[0][0];          // wl[0] dead now
  if ((lane & 31) == 0) denl[gr] = den;
  __syncthreads();
#pragma unroll
  for (int r = 0; r < 4; ++r) {             // C/D: row=(lane>>4)*4+r, col=lane&15
    const int row = kg * 4 + r;
    out[(size_t)(i0 + row) * FF + bcol] = acc[r] / denl[row];
  }
}

extern "C" void kernel_launch(void* const* d_in, const int* in_sizes, int n_in,
                              void* d_out, int out_size, void* d_ws, size_t ws_size,
                              hipStream_t stream) {
  const float* x   = (const float*)d_in[0];
  const float* adj = (const float*)d_in[1];
  const float* Wm  = (const float*)d_in[2];
  const float* av  = (const float*)d_in[3];
  float* out = (float*)d_out;

  char* ws = (char*)d_ws;
  u16*   hT  = (u16*)(ws);                       // 2 MB
  float* s1v = (float*)(ws + 2097152);           // 32 KB
  float* s2v = (float*)(ws + 2130048 - 128);     // keep 16B-align: 2129920
  u16*   xb  = (u16*)(ws + 2162688);             // 4 MB
  u16*   WTb = (u16*)(ws + 6356992);             // 64 KB

  wt_cvt  <<<2176, 256, 0, stream>>>(x, Wm, xb, WTb);
  gat_h   <<<NN / 16, 256, 0, stream>>>(xb, WTb, av, hT, s1v, s2v);
  gat_main<<<NN / 16, 512, 0, stream>>>(adj, hT, s1v, s2v, out);
}